// Round 11
// baseline (150.149 us; speedup 1.0000x reference)
//
#include <hip/hip_runtime.h>

// out = sigmoid(alpha)[:,None] * 0.5 * (ax - x) + x0
// ax = segment_sum(adj_values[:,None] * x[adj_col], adj_row)
//
// R11: (1) bucket_scan kernel deleted -- each bin block redundantly scans
// bhist in LDS (global slots via boffs_local + atomicAdd on a zeroed cursor);
// bin block 0 publishes boffs. (2) bin ACHUNK 4096->2048: 782 blocks, 53KB
// LDS -> 3 blocks/CU. (3) fused gather: nontemporal x0 load / out store so
// the 102MB of pure streams don't evict L2/L3-resident xb during the gather.

#define DIM 128
#define RPB 64               // rows per bucket (power of 2); shift = 6
#define RSHIFT 6
#define ACHUNK 2048          // edges per bin block
#define BCAP 2048            // fused-kernel LDS sort capacity (entries)
#define NBMAX 2048           // max buckets (N <= 131072)
#define HISTB 128            // hist blocks appended to xcast grid

typedef float f2v __attribute__((ext_vector_type(2)));

__device__ __forceinline__ float sigmoidf_(float a) {
    return 1.0f / (1.0f + __expf(-a));
}
__device__ __forceinline__ unsigned f2bf(float f) {   // fp32 -> bf16 (RNE)
    unsigned u = __float_as_uint(f);
    return (u + 0x7FFFu + ((u >> 16) & 1u)) >> 16;
}

// combined: blocks [0,xg) cast x->bf16; blocks [xg, xg+HISTB) histogram rows
// into NBMAX buckets (LDS-staged).
__global__ __launch_bounds__(256)
void xcast_hist_kernel(const float* __restrict__ x,
                       unsigned short* __restrict__ xb, int n4,
                       const int* __restrict__ row, int* __restrict__ bhist,
                       int n_edges, int nb, int xg) {
    __shared__ int h[NBMAX];
    if ((int)blockIdx.x < xg) {
        int i = blockIdx.x * 256 + threadIdx.x;
        if (i >= n4) return;
        float4 v = reinterpret_cast<const float4*>(x)[i];
        uint2 o;
        o.x = f2bf(v.x) | (f2bf(v.y) << 16);
        o.y = f2bf(v.z) | (f2bf(v.w) << 16);
        reinterpret_cast<uint2*>(xb)[i] = o;
        return;
    }
    int t = threadIdx.x;
    int bid = blockIdx.x - xg;
    for (int i = t; i < NBMAX; i += 256) h[i] = 0;
    __syncthreads();
    int e4 = n_edges >> 2;
    for (int i = bid * 256 + t; i < e4; i += HISTB * 256) {
        int4 r = reinterpret_cast<const int4*>(row)[i];
        atomicAdd(&h[r.x >> RSHIFT], 1);
        atomicAdd(&h[r.y >> RSHIFT], 1);
        atomicAdd(&h[r.z >> RSHIFT], 1);
        atomicAdd(&h[r.w >> RSHIFT], 1);
    }
    if (bid == 0 && t == 0) {
        for (int i = e4 << 2; i < n_edges; ++i)
            atomicAdd(&bhist[row[i] >> RSHIFT], 1);
    }
    __syncthreads();
    for (int i = t; i < NBMAX; i += 256)
        if (h[i]) atomicAdd(&bhist[i], h[i]);
}

// bin edges into RPB-row buckets. Each block: (a) scans global bhist in LDS
// (exclusive, 8/thread over 2048) -> SH; block 0 publishes boffs; (b) local
// chunk hist + scan -> lbase; (c) reserves global slices via gcur atomics;
// (d) LDS counting scatter; (e) coalesced write-out.
// epackA entry: ((localrow<<17)|col, valbits)
__global__ __launch_bounds__(256)
void bin_kernel(const int* __restrict__ row, const int* __restrict__ col,
                const float* __restrict__ vals,
                const int* __restrict__ bhist, int* __restrict__ gcur,
                int* __restrict__ boffs,
                int2* __restrict__ epackA, int n_edges, int nb) {
    __shared__ int hist[NBMAX];
    __shared__ int lbase[NBMAX];
    __shared__ int gbase[NBMAX];
    __shared__ int SH[NBMAX];            // global excl scan, then lcur
    __shared__ int ts[256];
    __shared__ int2 stage[ACHUNK];
    __shared__ unsigned short bkid[ACHUNK];
    int t = threadIdx.x;
    int base = blockIdx.x * ACHUNK;
    int m = n_edges - base;
    if (m > ACHUNK) m = ACHUNK;
    for (int i = t; i < NBMAX; i += 256) hist[i] = 0;
    __syncthreads();
    for (int i = t; i < m; i += 256)
        atomicAdd(&hist[row[base + i] >> RSHIFT], 1);
    // global scan of bhist (independent of local hist atomics in flight for
    // other threads? need hist done before local scan only) -- do global now
    int tb = t * 8;
    int gh[8];
    int grun = 0;
#pragma unroll
    for (int j = 0; j < 8; ++j) { gh[j] = bhist[tb + j]; grun += gh[j]; }
    ts[t] = grun;
    __syncthreads();
    for (int off = 1; off < 256; off <<= 1) {
        int u = (t >= off) ? ts[t - off] : 0;
        __syncthreads();
        ts[t] += u;
        __syncthreads();
    }
    {
        int ex = (t == 0) ? 0 : ts[t - 1];
#pragma unroll
        for (int j = 0; j < 8; ++j) { SH[tb + j] = ex; ex += gh[j]; }
    }
    __syncthreads();
    if (blockIdx.x == 0) {
        for (int i = t; i <= nb; i += 256)
            boffs[i] = (i < NBMAX) ? SH[i] : n_edges;
    }
    // local scan of chunk hist
    int lh[8];
    int lrun = 0;
#pragma unroll
    for (int j = 0; j < 8; ++j) { lh[j] = hist[tb + j]; lrun += lh[j]; }
    ts[t] = lrun;
    __syncthreads();
    for (int off = 1; off < 256; off <<= 1) {
        int u = (t >= off) ? ts[t - off] : 0;
        __syncthreads();
        ts[t] += u;
        __syncthreads();
    }
    {
        int ex = (t == 0) ? 0 : ts[t - 1];
#pragma unroll
        for (int j = 0; j < 8; ++j) { lbase[tb + j] = ex; ex += lh[j]; }
    }
    __syncthreads();
    // reserve global slices: gbase = SH + old cursor
    for (int i = t; i < nb; i += 256) {
        int hv = hist[i];
        gbase[i] = SH[i] + (hv ? atomicAdd(&gcur[i], hv) : 0);
    }
    __syncthreads();
    for (int i = t; i < NBMAX; i += 256) SH[i] = 0;   // SH becomes lcur
    __syncthreads();
    for (int i = t; i < m; i += 256) {
        int r = row[base + i];
        int c = col[base + i];
        float v = vals[base + i];
        int bk = r >> RSHIFT;
        int lp = atomicAdd(&SH[bk], 1);
        int sp = lbase[bk] + lp;
        stage[sp] = make_int2(((r & (RPB - 1)) << 17) | c, __float_as_int(v));
        bkid[sp] = (unsigned short)bk;
    }
    __syncthreads();
    for (int i = t; i < m; i += 256) {
        int bk = bkid[i];
        epackA[gbase[bk] + (i - lbase[bk])] = stage[i];
    }
}

// Fused sort+gather: one 512-thread block per 64-row bucket.
//  1) hist localrow over the bucket's epackA slice
//  2) 64-wide LDS scan -> row starts (stay in LDS)
//  3) scatter sorted (col,val) into eout[] in LDS
//  4) 8 waves x 8 rows: acc = x0 - s*x(bf16); loop edges (meta via LDS
//     broadcast, 8-deep pipelined row gathers); NT store out row.
template <int USE_BF16>
__global__ __launch_bounds__(512)
void fused_sort_gather_kernel(const unsigned short* __restrict__ xb,
                              const float* __restrict__ x,
                              const float* __restrict__ x0,
                              const float* __restrict__ alpha,
                              const int* __restrict__ boffs,
                              const int2* __restrict__ epackA,
                              float* __restrict__ out, int n_nodes) {
    __shared__ int2 eout[BCAP];
    __shared__ int rowstart[RPB];
    __shared__ int rowcur[RPB];
    __shared__ float sval[RPB];
    int b = blockIdx.x, t = threadIdx.x;
    int r0 = b * RPB;
    int begin = boffs[b], end = boffs[b + 1];
    int n = end - begin;
    if (t < RPB) {
        int r = r0 + t;
        sval[t] = (r < n_nodes) ? 0.5f * sigmoidf_(alpha[r]) : 0.f;
        rowstart[t] = 0;
    }
    __syncthreads();
    int wave = t >> 6, lane = t & 63;
    const unsigned* xbp = reinterpret_cast<const unsigned*>(xb);
    const float2* xp = reinterpret_cast<const float2*>(x);
    const f2v* x0v = reinterpret_cast<const f2v*>(x0);
    f2v* outv = reinterpret_cast<f2v*>(out);
    if (n <= BCAP) {
        for (int i = t; i < n; i += 512)
            atomicAdd(&rowstart[epackA[begin + i].x >> 17], 1);
        __syncthreads();
        if (t < RPB) rowcur[t] = rowstart[t];
        __syncthreads();
        for (int off = 1; off < RPB; off <<= 1) {
            int u = (t < RPB && t >= off) ? rowcur[t - off] : 0;
            __syncthreads();
            if (t < RPB) rowcur[t] += u;
            __syncthreads();
        }
        if (t < RPB) {
            int excl = rowcur[t] - rowstart[t];   // inclusive -> exclusive
            rowstart[t] = excl;
            rowcur[t] = excl;
        }
        __syncthreads();
        for (int i = t; i < n; i += 512) {
            int2 e = epackA[begin + i];
            int pos = atomicAdd(&rowcur[e.x >> 17], 1);
            eout[pos] = make_int2(e.x & 0x1FFFF, e.y);
        }
        __syncthreads();
        for (int q = 0; q < 8; ++q) {
            int lr = wave * 8 + q;
            int r = r0 + lr;
            if (r >= n_nodes) break;
            float s = sval[lr];
            int rb = r * 64;
            f2v a0 = __builtin_nontemporal_load(&x0v[rb + lane]);
            float2 acc = make_float2(a0.x, a0.y);
            if (USE_BF16) {
                unsigned dx = xbp[rb + lane];
                acc.x -= s * __uint_as_float((dx & 0xFFFFu) << 16);
                acc.y -= s * __uint_as_float(dx & 0xFFFF0000u);
            } else {
                float2 xv = xp[rb + lane];
                acc.x -= s * xv.x;
                acc.y -= s * xv.y;
            }
            int k = rowstart[lr];
            int stop = (lr + 1 < RPB) ? rowstart[lr + 1] : n;
            for (; k + 8 <= stop; k += 8) {
                float w[8];
                if (USE_BF16) {
                    unsigned d[8];
#pragma unroll
                    for (int j = 0; j < 8; ++j) {
                        int2 e = eout[k + j];
                        w[j] = s * __int_as_float(e.y);
                        d[j] = xbp[(size_t)e.x * 64 + lane];
                    }
#pragma unroll
                    for (int j = 0; j < 8; ++j) {
                        acc.x += w[j] * __uint_as_float((d[j] & 0xFFFFu) << 16);
                        acc.y += w[j] * __uint_as_float(d[j] & 0xFFFF0000u);
                    }
                } else {
                    float2 v[8];
#pragma unroll
                    for (int j = 0; j < 8; ++j) {
                        int2 e = eout[k + j];
                        w[j] = s * __int_as_float(e.y);
                        v[j] = xp[(size_t)e.x * 64 + lane];
                    }
#pragma unroll
                    for (int j = 0; j < 8; ++j) {
                        acc.x += w[j] * v[j].x;
                        acc.y += w[j] * v[j].y;
                    }
                }
            }
            for (; k < stop; ++k) {
                int2 e = eout[k];
                float w = s * __int_as_float(e.y);
                if (USE_BF16) {
                    unsigned d = xbp[(size_t)e.x * 64 + lane];
                    acc.x += w * __uint_as_float((d & 0xFFFFu) << 16);
                    acc.y += w * __uint_as_float(d & 0xFFFF0000u);
                } else {
                    float2 v = xp[(size_t)e.x * 64 + lane];
                    acc.x += w * v.x;
                    acc.y += w * v.y;
                }
            }
            f2v o; o.x = acc.x; o.y = acc.y;
            __builtin_nontemporal_store(o, &outv[rb + lane]);
        }
    } else {
        // correctness-only fallback (unreachable for ~1k-edge buckets)
        for (int q = 0; q < 8; ++q) {
            int lr = wave * 8 + q;
            int r = r0 + lr;
            if (r >= n_nodes) break;
            float s = sval[lr];
            int rb = r * 64;
            float2 acc = reinterpret_cast<const float2*>(x0)[rb + lane];
            if (USE_BF16) {
                unsigned dx = xbp[rb + lane];
                acc.x -= s * __uint_as_float((dx & 0xFFFFu) << 16);
                acc.y -= s * __uint_as_float(dx & 0xFFFF0000u);
            } else {
                float2 xv = xp[rb + lane];
                acc.x -= s * xv.x;
                acc.y -= s * xv.y;
            }
            for (int i = 0; i < n; ++i) {
                int2 e = epackA[begin + i];
                if ((e.x >> 17) == lr) {
                    float w = s * __int_as_float(e.y);
                    if (USE_BF16) {
                        unsigned d = xbp[(size_t)(e.x & 0x1FFFF) * 64 + lane];
                        acc.x += w * __uint_as_float((d & 0xFFFFu) << 16);
                        acc.y += w * __uint_as_float(d & 0xFFFF0000u);
                    } else {
                        float2 v = xp[(size_t)(e.x & 0x1FFFF) * 64 + lane];
                        acc.x += w * v.x;
                        acc.y += w * v.y;
                    }
                }
            }
            reinterpret_cast<float2*>(out)[rb + lane] = acc;
        }
    }
}

extern "C" void kernel_launch(void* const* d_in, const int* in_sizes, int n_in,
                              void* d_out, int out_size, void* d_ws, size_t ws_size,
                              hipStream_t stream) {
    // inputs: 0=t(unused), 1=x[N,D], 2=x0[N,D], 3=alpha[N], 4=vals[E],
    //         5=row[E](i32), 6=col[E](i32)
    const float* x     = (const float*)d_in[1];
    const float* x0    = (const float*)d_in[2];
    const float* alpha = (const float*)d_in[3];
    const float* vals  = (const float*)d_in[4];
    const int*   row   = (const int*)d_in[5];
    const int*   col   = (const int*)d_in[6];
    float* out = (float*)d_out;

    int n_nodes = in_sizes[3];
    int n_edges = in_sizes[4];
    int nb = (n_nodes + RPB - 1) / RPB;            // 1563 buckets

    // workspace layout: xb FIRST (256B-aligned -> minimal gather granules)
    size_t xb_bytes = (size_t)n_nodes * DIM * sizeof(unsigned short);
    size_t ep_bytes = (size_t)((n_edges + 3) & ~3) * sizeof(int2);
    size_t meta_bytes = (size_t)(NBMAX + NBMAX + NBMAX + 16) * sizeof(int);
    int use_bf16 = (ws_size >= xb_bytes + ep_bytes + meta_bytes + 512) ? 1 : 0;

    unsigned short* xxb;
    int2* epackA;
    int* bhist;
    if (use_bf16) {
        xxb    = (unsigned short*)d_ws;
        epackA = (int2*)((char*)d_ws + xb_bytes);
        bhist  = (int*)((char*)epackA + ep_bytes);
    } else {
        xxb    = nullptr;
        epackA = (int2*)d_ws;
        bhist  = (int*)((char*)epackA + ep_bytes);
    }
    int* gcur  = bhist + NBMAX;                    // NBMAX (zeroed)
    int* boffs = gcur + NBMAX;                     // NBMAX+16

    hipMemsetAsync(bhist, 0, 2 * NBMAX * sizeof(int), stream);  // bhist+gcur

    {
        int n4 = use_bf16 ? ((n_nodes * DIM) >> 2) : 0;
        int xg = use_bf16 ? ((n4 + 255) / 256) : 0;
        xcast_hist_kernel<<<xg + HISTB, 256, 0, stream>>>(
            x, xxb, n4, row, bhist, n_edges, nb, xg);
    }
    {
        int grid = (n_edges + ACHUNK - 1) / ACHUNK;
        bin_kernel<<<grid, 256, 0, stream>>>(row, col, vals, bhist, gcur,
                                             boffs, epackA, n_edges, nb);
    }
    if (use_bf16) {
        fused_sort_gather_kernel<1><<<nb, 512, 0, stream>>>(
            xxb, x, x0, alpha, boffs, epackA, out, n_nodes);
    } else {
        fused_sort_gather_kernel<0><<<nb, 512, 0, stream>>>(
            xxb, x, x0, alpha, boffs, epackA, out, n_nodes);
    }
}

// Round 12
// 139.834 us; speedup vs baseline: 1.0738x; 1.0738x over previous
//
#include <hip/hip_runtime.h>

// out = sigmoid(alpha)[:,None] * 0.5 * (ax - x) + x0
// ax = segment_sum(adj_values[:,None] * x[adj_col], adj_row)
//
// R12: recombination. R11's per-block redundant bhist scan cost +23us of
// preprocessing (782 blocks x 2048-entry scan) to save a 4us kernel -- revert
// to R10's pipeline {xcast_hist -> 1-block bucket_scan -> bin ACHUNK=4096}.
// Keep R11's fused-kernel wins: nontemporal x0 load / out store (fused 92->84.5,
// FETCH 233->212MB). RPB=64 (1563 buckets), xb at ws offset 0 (256B-aligned).

#define DIM 128
#define RPB 64               // rows per bucket (power of 2); shift = 6
#define RSHIFT 6
#define ACHUNK 4096          // edges per bin block
#define BCAP 2048            // fused-kernel LDS sort capacity (entries)
#define NBMAX 2048           // max buckets (N <= 131072)
#define HISTB 128            // hist blocks appended to xcast grid

typedef float f2v __attribute__((ext_vector_type(2)));

__device__ __forceinline__ float sigmoidf_(float a) {
    return 1.0f / (1.0f + __expf(-a));
}
__device__ __forceinline__ unsigned f2bf(float f) {   // fp32 -> bf16 (RNE)
    unsigned u = __float_as_uint(f);
    return (u + 0x7FFFu + ((u >> 16) & 1u)) >> 16;
}

// combined: blocks [0,xg) cast x->bf16; blocks [xg, xg+HISTB) histogram rows
// into NBMAX buckets (LDS-staged).
__global__ __launch_bounds__(256)
void xcast_hist_kernel(const float* __restrict__ x,
                       unsigned short* __restrict__ xb, int n4,
                       const int* __restrict__ row, int* __restrict__ bhist,
                       int n_edges, int nb, int xg) {
    __shared__ int h[NBMAX];
    if ((int)blockIdx.x < xg) {
        int i = blockIdx.x * 256 + threadIdx.x;
        if (i >= n4) return;
        float4 v = reinterpret_cast<const float4*>(x)[i];
        uint2 o;
        o.x = f2bf(v.x) | (f2bf(v.y) << 16);
        o.y = f2bf(v.z) | (f2bf(v.w) << 16);
        reinterpret_cast<uint2*>(xb)[i] = o;
        return;
    }
    int t = threadIdx.x;
    int bid = blockIdx.x - xg;
    for (int i = t; i < NBMAX; i += 256) h[i] = 0;
    __syncthreads();
    int e4 = n_edges >> 2;
    for (int i = bid * 256 + t; i < e4; i += HISTB * 256) {
        int4 r = reinterpret_cast<const int4*>(row)[i];
        atomicAdd(&h[r.x >> RSHIFT], 1);
        atomicAdd(&h[r.y >> RSHIFT], 1);
        atomicAdd(&h[r.z >> RSHIFT], 1);
        atomicAdd(&h[r.w >> RSHIFT], 1);
    }
    if (bid == 0 && t == 0) {
        for (int i = e4 << 2; i < n_edges; ++i)
            atomicAdd(&bhist[row[i] >> RSHIFT], 1);
    }
    __syncthreads();
    for (int i = t; i < NBMAX; i += 256)
        if (h[i]) atomicAdd(&bhist[i], h[i]);
}

// single-block exclusive scan of bhist[0..nb) -> boffs[0..nb], bcur copy
// (nb <= 2048: 2 elements per thread)
__global__ __launch_bounds__(1024)
void bucket_scan_kernel(const int* __restrict__ bhist, int* __restrict__ boffs,
                        int* __restrict__ bcur, int nb) {
    __shared__ int ts[1024];
    int t = threadIdx.x;
    int i0 = 2 * t, i1 = 2 * t + 1;
    int v0 = (i0 < nb) ? bhist[i0] : 0;
    int v1 = (i1 < nb) ? bhist[i1] : 0;
    ts[t] = v0 + v1;
    __syncthreads();
    for (int off = 1; off < 1024; off <<= 1) {
        int u = (t >= off) ? ts[t - off] : 0;
        __syncthreads();
        ts[t] += u;
        __syncthreads();
    }
    int ex = (t == 0) ? 0 : ts[t - 1];
    if (i0 < nb) { boffs[i0] = ex;      bcur[i0] = ex; }
    if (i1 < nb) { boffs[i1] = ex + v0; bcur[i1] = ex + v0; }
    if (t == 1023) boffs[nb] = ts[1023];
}

// bin edges into RPB-row buckets, LDS-staged so global writes are runs of
// consecutive slots. epackA entry: ((localrow<<17)|col, valbits)
__global__ __launch_bounds__(256)
void bin_kernel(const int* __restrict__ row, const int* __restrict__ col,
                const float* __restrict__ vals, int* __restrict__ bcursor,
                int2* __restrict__ epackA, int n_edges, int nb) {
    __shared__ int hist[NBMAX];
    __shared__ int lbase[NBMAX];
    __shared__ int gbase[NBMAX];
    __shared__ int lcur[NBMAX];
    __shared__ int ts[256];
    __shared__ int2 stage[ACHUNK];
    __shared__ unsigned short bkid[ACHUNK];
    int t = threadIdx.x;
    int base = blockIdx.x * ACHUNK;
    int m = n_edges - base;
    if (m > ACHUNK) m = ACHUNK;
    for (int i = t; i < NBMAX; i += 256) hist[i] = 0;
    __syncthreads();
    for (int i = t; i < m; i += 256)
        atomicAdd(&hist[row[base + i] >> RSHIFT], 1);
    __syncthreads();
    // 8-per-thread exclusive scan over NBMAX=2048
    int tb = t * 8;
    int hh[8];
    int run = 0;
#pragma unroll
    for (int j = 0; j < 8; ++j) { hh[j] = hist[tb + j]; run += hh[j]; }
    ts[t] = run;
    __syncthreads();
    for (int off = 1; off < 256; off <<= 1) {
        int u = (t >= off) ? ts[t - off] : 0;
        __syncthreads();
        ts[t] += u;
        __syncthreads();
    }
    int ex = (t == 0) ? 0 : ts[t - 1];
#pragma unroll
    for (int j = 0; j < 8; ++j) { lbase[tb + j] = ex; ex += hh[j]; }
    __syncthreads();
    for (int i = t; i < nb; i += 256) {
        int hv = hist[i];
        gbase[i] = hv ? atomicAdd(&bcursor[i], hv) : 0;
        lcur[i] = 0;
    }
    __syncthreads();
    for (int i = t; i < m; i += 256) {
        int r = row[base + i];
        int c = col[base + i];
        float v = vals[base + i];
        int bk = r >> RSHIFT;
        int lp = atomicAdd(&lcur[bk], 1);
        int sp = lbase[bk] + lp;
        stage[sp] = make_int2(((r & (RPB - 1)) << 17) | c, __float_as_int(v));
        bkid[sp] = (unsigned short)bk;
    }
    __syncthreads();
    for (int i = t; i < m; i += 256) {
        int bk = bkid[i];
        epackA[gbase[bk] + (i - lbase[bk])] = stage[i];
    }
}

// Fused sort+gather: one 512-thread block per 64-row bucket.
//  1) hist localrow over the bucket's epackA slice
//  2) 64-wide LDS scan -> row starts (stay in LDS)
//  3) scatter sorted (col,val) into eout[] in LDS
//  4) 8 waves x 8 rows: acc = x0(NT) - s*x(bf16); loop edges (meta via LDS
//     broadcast, 8-deep pipelined row gathers); NT store out row.
template <int USE_BF16>
__global__ __launch_bounds__(512)
void fused_sort_gather_kernel(const unsigned short* __restrict__ xb,
                              const float* __restrict__ x,
                              const float* __restrict__ x0,
                              const float* __restrict__ alpha,
                              const int* __restrict__ boffs,
                              const int2* __restrict__ epackA,
                              float* __restrict__ out, int n_nodes) {
    __shared__ int2 eout[BCAP];
    __shared__ int rowstart[RPB];
    __shared__ int rowcur[RPB];
    __shared__ float sval[RPB];
    int b = blockIdx.x, t = threadIdx.x;
    int r0 = b * RPB;
    int begin = boffs[b], end = boffs[b + 1];
    int n = end - begin;
    if (t < RPB) {
        int r = r0 + t;
        sval[t] = (r < n_nodes) ? 0.5f * sigmoidf_(alpha[r]) : 0.f;
        rowstart[t] = 0;
    }
    __syncthreads();
    int wave = t >> 6, lane = t & 63;
    const unsigned* xbp = reinterpret_cast<const unsigned*>(xb);
    const float2* xp = reinterpret_cast<const float2*>(x);
    const f2v* x0v = reinterpret_cast<const f2v*>(x0);
    f2v* outv = reinterpret_cast<f2v*>(out);
    if (n <= BCAP) {
        for (int i = t; i < n; i += 512)
            atomicAdd(&rowstart[epackA[begin + i].x >> 17], 1);
        __syncthreads();
        if (t < RPB) rowcur[t] = rowstart[t];
        __syncthreads();
        for (int off = 1; off < RPB; off <<= 1) {
            int u = (t < RPB && t >= off) ? rowcur[t - off] : 0;
            __syncthreads();
            if (t < RPB) rowcur[t] += u;
            __syncthreads();
        }
        if (t < RPB) {
            int excl = rowcur[t] - rowstart[t];   // inclusive -> exclusive
            rowstart[t] = excl;
            rowcur[t] = excl;
        }
        __syncthreads();
        for (int i = t; i < n; i += 512) {
            int2 e = epackA[begin + i];
            int pos = atomicAdd(&rowcur[e.x >> 17], 1);
            eout[pos] = make_int2(e.x & 0x1FFFF, e.y);
        }
        __syncthreads();
        for (int q = 0; q < 8; ++q) {
            int lr = wave * 8 + q;
            int r = r0 + lr;
            if (r >= n_nodes) break;
            float s = sval[lr];
            int rb = r * 64;
            f2v a0 = __builtin_nontemporal_load(&x0v[rb + lane]);
            float2 acc = make_float2(a0.x, a0.y);
            if (USE_BF16) {
                unsigned dx = xbp[rb + lane];
                acc.x -= s * __uint_as_float((dx & 0xFFFFu) << 16);
                acc.y -= s * __uint_as_float(dx & 0xFFFF0000u);
            } else {
                float2 xv = xp[rb + lane];
                acc.x -= s * xv.x;
                acc.y -= s * xv.y;
            }
            int k = rowstart[lr];
            int stop = (lr + 1 < RPB) ? rowstart[lr + 1] : n;
            for (; k + 8 <= stop; k += 8) {
                float w[8];
                if (USE_BF16) {
                    unsigned d[8];
#pragma unroll
                    for (int j = 0; j < 8; ++j) {
                        int2 e = eout[k + j];
                        w[j] = s * __int_as_float(e.y);
                        d[j] = xbp[(size_t)e.x * 64 + lane];
                    }
#pragma unroll
                    for (int j = 0; j < 8; ++j) {
                        acc.x += w[j] * __uint_as_float((d[j] & 0xFFFFu) << 16);
                        acc.y += w[j] * __uint_as_float(d[j] & 0xFFFF0000u);
                    }
                } else {
                    float2 v[8];
#pragma unroll
                    for (int j = 0; j < 8; ++j) {
                        int2 e = eout[k + j];
                        w[j] = s * __int_as_float(e.y);
                        v[j] = xp[(size_t)e.x * 64 + lane];
                    }
#pragma unroll
                    for (int j = 0; j < 8; ++j) {
                        acc.x += w[j] * v[j].x;
                        acc.y += w[j] * v[j].y;
                    }
                }
            }
            for (; k < stop; ++k) {
                int2 e = eout[k];
                float w = s * __int_as_float(e.y);
                if (USE_BF16) {
                    unsigned d = xbp[(size_t)e.x * 64 + lane];
                    acc.x += w * __uint_as_float((d & 0xFFFFu) << 16);
                    acc.y += w * __uint_as_float(d & 0xFFFF0000u);
                } else {
                    float2 v = xp[(size_t)e.x * 64 + lane];
                    acc.x += w * v.x;
                    acc.y += w * v.y;
                }
            }
            f2v o; o.x = acc.x; o.y = acc.y;
            __builtin_nontemporal_store(o, &outv[rb + lane]);
        }
    } else {
        // correctness-only fallback (unreachable for ~1k-edge buckets)
        for (int q = 0; q < 8; ++q) {
            int lr = wave * 8 + q;
            int r = r0 + lr;
            if (r >= n_nodes) break;
            float s = sval[lr];
            int rb = r * 64;
            float2 acc = reinterpret_cast<const float2*>(x0)[rb + lane];
            if (USE_BF16) {
                unsigned dx = xbp[rb + lane];
                acc.x -= s * __uint_as_float((dx & 0xFFFFu) << 16);
                acc.y -= s * __uint_as_float(dx & 0xFFFF0000u);
            } else {
                float2 xv = xp[rb + lane];
                acc.x -= s * xv.x;
                acc.y -= s * xv.y;
            }
            for (int i = 0; i < n; ++i) {
                int2 e = epackA[begin + i];
                if ((e.x >> 17) == lr) {
                    float w = s * __int_as_float(e.y);
                    if (USE_BF16) {
                        unsigned d = xbp[(size_t)(e.x & 0x1FFFF) * 64 + lane];
                        acc.x += w * __uint_as_float((d & 0xFFFFu) << 16);
                        acc.y += w * __uint_as_float(d & 0xFFFF0000u);
                    } else {
                        float2 v = xp[(size_t)(e.x & 0x1FFFF) * 64 + lane];
                        acc.x += w * v.x;
                        acc.y += w * v.y;
                    }
                }
            }
            reinterpret_cast<float2*>(out)[rb + lane] = acc;
        }
    }
}

extern "C" void kernel_launch(void* const* d_in, const int* in_sizes, int n_in,
                              void* d_out, int out_size, void* d_ws, size_t ws_size,
                              hipStream_t stream) {
    // inputs: 0=t(unused), 1=x[N,D], 2=x0[N,D], 3=alpha[N], 4=vals[E],
    //         5=row[E](i32), 6=col[E](i32)
    const float* x     = (const float*)d_in[1];
    const float* x0    = (const float*)d_in[2];
    const float* alpha = (const float*)d_in[3];
    const float* vals  = (const float*)d_in[4];
    const int*   row   = (const int*)d_in[5];
    const int*   col   = (const int*)d_in[6];
    float* out = (float*)d_out;

    int n_nodes = in_sizes[3];
    int n_edges = in_sizes[4];
    int nb = (n_nodes + RPB - 1) / RPB;            // 1563 buckets

    // workspace layout: xb FIRST (256B-aligned -> minimal gather granules)
    size_t xb_bytes = (size_t)n_nodes * DIM * sizeof(unsigned short);
    size_t ep_bytes = (size_t)((n_edges + 3) & ~3) * sizeof(int2);
    size_t meta_bytes = (size_t)(NBMAX + NBMAX + 16 + NBMAX) * sizeof(int);
    int use_bf16 = (ws_size >= xb_bytes + ep_bytes + meta_bytes + 512) ? 1 : 0;

    unsigned short* xxb;
    int2* epackA;
    int* bhist;
    if (use_bf16) {
        xxb    = (unsigned short*)d_ws;
        epackA = (int2*)((char*)d_ws + xb_bytes);
        bhist  = (int*)((char*)epackA + ep_bytes);
    } else {
        xxb    = nullptr;
        epackA = (int2*)d_ws;
        bhist  = (int*)((char*)epackA + ep_bytes);
    }
    int* boffs = bhist + NBMAX;                    // NBMAX+16
    int* bcur  = boffs + NBMAX + 16;               // NBMAX

    hipMemsetAsync(bhist, 0, NBMAX * sizeof(int), stream);

    {
        int n4 = use_bf16 ? ((n_nodes * DIM) >> 2) : 0;
        int xg = use_bf16 ? ((n4 + 255) / 256) : 0;
        xcast_hist_kernel<<<xg + HISTB, 256, 0, stream>>>(
            x, xxb, n4, row, bhist, n_edges, nb, xg);
    }
    bucket_scan_kernel<<<1, 1024, 0, stream>>>(bhist, boffs, bcur, nb);
    {
        int grid = (n_edges + ACHUNK - 1) / ACHUNK;
        bin_kernel<<<grid, 256, 0, stream>>>(row, col, vals, bcur, epackA,
                                             n_edges, nb);
    }
    if (use_bf16) {
        fused_sort_gather_kernel<1><<<nb, 512, 0, stream>>>(
            xxb, x, x0, alpha, boffs, epackA, out, n_nodes);
    } else {
        fused_sort_gather_kernel<0><<<nb, 512, 0, stream>>>(
            xxb, x, x0, alpha, boffs, epackA, out, n_nodes);
    }
}